// Round 13
// baseline (61.018 us; speedup 1.0000x reference)
//
#include <hip/hip_runtime.h>
#include <math.h>

#define NRAYS 512
#define NSAMP 64
#define IMH 480
#define IMW 640
#define NFEAT 256
#define ZNEAR 0.7f
#define ZFAR 1.5f
#define KU1 288          // W1 row length (ushorts): k-map 0-8 meta, 9-15 zero, 16-271 feats, 272-287 zero
#define W1LO 36864       // ushort offset of W1 lo plane
#define W2OF 73728       // ushort offset of W2 hi plane
#define W2LO 16384       // relative ushort offset of W2 lo plane
#define H1S 132          // h1 packed row stride (u32)
#define STGS 36          // x staging row stride (u32)
#define WROW 40          // LDS W-chunk row stride (ushorts, 80B)
#define WPLANE 5120      // 128*WROW: lo-plane offset within a chunk buffer (ushorts)
#define WBUF 10240       // one chunk buffer = 2 planes (ushorts)

typedef __attribute__((ext_vector_type(8))) short bf16x8;
typedef __attribute__((ext_vector_type(16))) float f32x16;

__device__ __forceinline__ unsigned short bf16rne(float f) {
    unsigned int u = __builtin_bit_cast(unsigned int, f);
    unsigned int r = (u + 0x7FFFu + ((u >> 16) & 1u)) >> 16;
    return (unsigned short)r;
}
__device__ __forceinline__ float bf16tof(unsigned short h) {
    unsigned int u = ((unsigned int)h) << 16;
    return __builtin_bit_cast(float, u);
}
__device__ __forceinline__ unsigned int packsplit(float v) {
    const unsigned short h = bf16rne(v);
    const unsigned short l = bf16rne(v - bf16tof(h));
    return (((unsigned int)h) << 16) | (unsigned int)l;
}
__device__ __forceinline__ void unpack8(uint4 a, uint4 b, bf16x8& hi, bf16x8& lo) {
    union { bf16x8 v; unsigned short u[8]; } H, L;
    const unsigned int w[8] = {a.x, a.y, a.z, a.w, b.x, b.y, b.z, b.w};
    #pragma unroll
    for (int i = 0; i < 8; ++i) {
        H.u[i] = (unsigned short)(w[i] >> 16);
        L.u[i] = (unsigned short)(w[i] & 0xFFFFu);
    }
    hi = H.v; lo = L.v;
}

// ---- prep: transpose + bf16-split W1 -> [128][288] and W2 -> [128][128] ----
__global__ __launch_bounds__(256)
void nerf_prep(const float* __restrict__ W1, const float* __restrict__ W2,
               unsigned short* __restrict__ wsu) {
    const int i = blockIdx.x * 256 + threadIdx.x;
    if (i < 36864) {
        const int n = i / KU1, k = i % KU1;
        float val = 0.0f;
        if (k < 9) val = W1[k * 128 + n];
        else if (k >= 16 && k < 272) val = W1[(k - 7) * 128 + n];
        const unsigned short h = bf16rne(val);
        wsu[n * KU1 + k] = h;
        wsu[W1LO + n * KU1 + k] = bf16rne(val - bf16tof(h));
    } else if (i < 53248) {
        const int j = i - 36864;
        const int n = j >> 7, k = j & 127;
        const float val = W2[k * 128 + n];
        const unsigned short h = bf16rne(val);
        wsu[W2OF + n * 128 + k] = h;
        wsu[W2OF + W2LO + n * 128 + k] = bf16rne(val - bf16tof(h));
    }
}

// ---- main: block = ray, 512 thr = 8 waves. Rows 0..127 = 2 views x 64
// samples. Wave w: M-tile mt=w>>1 (32 rows), N-half np=w&1 (2x 32-ch tiles).
// 32x32x16 MFMA: same B-bytes/lane as 16x16x32 but 2x FLOPs -> B LDS traffic
// halved. Pair (2mt,2mt+1) shares A-frags via pair x-staging published by the
// existing per-chunk W barrier (each wave still stages its own 16 rows).
// W global->LDS 32-dim chunks double-buffered, 3-pass split-bf16, fused render.
__global__ __launch_bounds__(512, 2)
void nerf_main(const float* __restrict__ rayo,
               const float* __restrict__ rayd,
               const float* __restrict__ images,
               const float* __restrict__ intr,
               const float* __restrict__ einv,
               const float* __restrict__ feats,
               const float* __restrict__ b1,
               const float* __restrict__ b2,
               const float* __restrict__ Wr,
               const float* __restrict__ br,
               const unsigned short* __restrict__ wsu,
               float* __restrict__ out) {
    __shared__ float s_meta[128][12];                // 6144B: o4 | wx wy | cam xyz
    __shared__ float s_cdir[2][4];
    __shared__ unsigned int h1p[128 * H1S];          // 67584B packed hi|lo
    __shared__ unsigned short ldsW[2 * WBUF];        // 40960B W-chunk dbuf
    __shared__ unsigned int xstg[4][2][32 * STGS];   // 36864B pair x-staging dbuf
    __shared__ float s_part[2][128][4];              // 4096B readout partials

    const int t = threadIdx.x;
    const int r = blockIdx.x;
    const int w8 = __builtin_amdgcn_readfirstlane(t >> 6);
    const int mt = w8 >> 1;                 // M-tile 0..3
    const int np = w8 & 1;                  // N-half
    const int lane = t & 63;
    const int l31 = lane & 31;
    const int lh = lane >> 5;
    const int sq = lane >> 2;               // staging row-within-16
    const int qq = lane & 3;                // staging dim-quad
    const int vW = w8 >> 2;                 // view of this wave's rows
    const int rit = np * 16 + sq;           // staged row within M-tile
    constexpr float STEP = (ZFAR - ZNEAR) / (NSAMP - 1);

    // W staging role: each thread moves 32B of a chunk
    const int sp = t >> 8;                  // plane
    const int sn = (t & 255) >> 1;          // row n
    const int sh = (t & 1) * 16;            // col half (ushorts)

    // issue W1 chunk 0 loads (hide under meta prep)
    uint4 wa, wb;
    {
        const unsigned short* s = wsu + sp*W1LO + sn*KU1 + sh;
        wa = *reinterpret_cast<const uint4*>(s);
        wb = *reinterpret_cast<const uint4*>(s + 8);
    }

    // ---- projection prep: threads 0..127 = global row (view, sample) ----
    if (t < 128) {
        const int vv = t >> 6, p = t & 63;
        const float ox = rayo[r*3+0], oy = rayo[r*3+1], oz = rayo[r*3+2];
        const float dx = rayd[r*3+0], dy = rayd[r*3+1], dz = rayd[r*3+2];
        const float z = ZNEAR + p * STEP;
        const float wxp = ox + z*dx, wyp = oy + z*dy, wzp = oz + z*dz;
        const float* E = einv + vv*16;
        const float cx = E[0]*wxp + E[1]*wyp + E[2]*wzp + E[3];
        const float cy = E[4]*wxp + E[5]*wyp + E[6]*wzp + E[7];
        const float cz = E[8]*wxp + E[9]*wyp + E[10]*wzp + E[11];
        const float cw = E[12]*wxp + E[13]*wyp + E[14]*wzp + E[15];
        const float* Km = intr + vv*16;
        const float px = Km[0]*cx + Km[1]*cy + Km[2]*cz + Km[3]*cw;
        const float py = Km[4]*cx + Km[5]*cy + Km[6]*cz + Km[7]*cw;
        const float pz = Km[8]*cx + Km[9]*cy + Km[10]*cz + Km[11]*cw;
        const float inv = pz + 1e-8f;
        float fx = px / inv, fy = py / inv;
        fx = fminf(fmaxf(fx, 0.0f), (float)(IMW-1));
        fy = fminf(fmaxf(fy, 0.0f), (float)(IMH-1));
        const int x0 = (int)floorf(fx), y0 = (int)floorf(fy);
        const int x1 = min(x0+1, IMW-1), y1 = min(y0+1, IMH-1);
        const int base = vv*IMH*IMW;
        int4 o4; o4.x = (base + y0*IMW + x0) * NFEAT;
                 o4.y = (base + y0*IMW + x1) * NFEAT;
                 o4.z = (base + y1*IMW + x0) * NFEAT;
                 o4.w = (base + y1*IMW + x1) * NFEAT;
        *(int4*)&s_meta[t][0] = o4;
        s_meta[t][4] = fx - (float)x0;
        s_meta[t][5] = fy - (float)y0;
        s_meta[t][6] = cx; s_meta[t][7] = cy; s_meta[t][8] = cz;
        if (p == 0) {
            s_cdir[vv][0] = E[0]*dx + E[1]*dy + E[2]*dz;
            s_cdir[vv][1] = E[4]*dx + E[5]*dy + E[6]*dz;
            s_cdir[vv][2] = E[8]*dx + E[9]*dy + E[10]*dz;
        }
    }
    // write W1 chunk 0 -> buffer 0 (covered by same barrier)
    {
        unsigned short* d = ldsW + sp*WPLANE + sn*WROW + sh;
        *reinterpret_cast<uint4*>(d)     = wa;
        *reinterpret_cast<uint4*>(d + 8) = wb;
    }
    __syncthreads();

    // ---- staging meta for this lane's row (w8*16 + sq) ----
    const float* mg = s_meta[w8*16 + sq];
    const int4 og = *(const int4*)mg;
    const float wx = mg[4], wy = mg[5];
    const float w00 = (1.f-wx)*(1.f-wy), w01 = wx*(1.f-wy);
    const float w10 = (1.f-wx)*wy,       w11 = wx*wy;
    const float* t00 = feats + og.x;
    const float* t01 = feats + og.y;
    const float* t10 = feats + og.z;
    const float* t11 = feats + og.w;

    float ia = 0.f, ib = 0.f;
    if (qq == 1 || qq == 2) {
        const int i00 = (og.x >> 8) * 3, i01 = (og.y >> 8) * 3;
        const int i10 = (og.z >> 8) * 3, i11 = (og.w >> 8) * 3;
        if (qq == 1) {
            ia = 2.0f*(w00*images[i00+0] + w01*images[i01+0] + w10*images[i10+0] + w11*images[i11+0]) - 1.0f;
            ib = 2.0f*(w00*images[i00+1] + w01*images[i01+1] + w10*images[i10+1] + w11*images[i11+1]) - 1.0f;
        } else {
            ia = 2.0f*(w00*images[i00+2] + w01*images[i01+2] + w10*images[i10+2] + w11*images[i11+2]) - 1.0f;
        }
    }

    float4 La[4], Lb[4];
    {   // texels chunk0 sub1 (dims 16-31 = feats 0-15)
        const int f1 = qq*4;
        Lb[0] = *reinterpret_cast<const float4*>(t00 + f1);
        Lb[1] = *reinterpret_cast<const float4*>(t01 + f1);
        Lb[2] = *reinterpret_cast<const float4*>(t10 + f1);
        Lb[3] = *reinterpret_cast<const float4*>(t11 + f1);
    }
    // ---- stage chunk 0 into pair buffer 0 ----
    {
        float f0[4], f1[4];
        if (qq == 0)      { f0[0]=mg[6]; f0[1]=mg[7]; f0[2]=mg[8]; f0[3]=s_cdir[vW][0]; }
        else if (qq == 1) { f0[0]=s_cdir[vW][1]; f0[1]=s_cdir[vW][2]; f0[2]=ia; f0[3]=ib; }
        else if (qq == 2) { f0[0]=ia; f0[1]=0.f; f0[2]=0.f; f0[3]=0.f; }
        else              { f0[0]=0.f; f0[1]=0.f; f0[2]=0.f; f0[3]=0.f; }
        f1[0] = w00*Lb[0].x + w01*Lb[1].x + w10*Lb[2].x + w11*Lb[3].x;
        f1[1] = w00*Lb[0].y + w01*Lb[1].y + w10*Lb[2].y + w11*Lb[3].y;
        f1[2] = w00*Lb[0].z + w01*Lb[1].z + w10*Lb[2].z + w11*Lb[3].z;
        f1[3] = w00*Lb[0].w + w01*Lb[1].w + w10*Lb[2].w + w11*Lb[3].w;
        uint4 u0, u1;
        u0.x = packsplit(f0[0]); u0.y = packsplit(f0[1]);
        u0.z = packsplit(f0[2]); u0.w = packsplit(f0[3]);
        u1.x = packsplit(f1[0]); u1.y = packsplit(f1[1]);
        u1.z = packsplit(f1[2]); u1.w = packsplit(f1[3]);
        unsigned int* xw = &xstg[mt][0][rit*STGS];
        *reinterpret_cast<uint4*>(xw + qq*4)      = u0;
        *reinterpret_cast<uint4*>(xw + 16 + qq*4) = u1;
    }
    {   // texels for chunk 1 (sub0 feats 16.., sub1 feats 32..)
        const int n0 = 16 + qq*4, n1 = 32 + qq*4;
        La[0] = *reinterpret_cast<const float4*>(t00 + n0);
        La[1] = *reinterpret_cast<const float4*>(t01 + n0);
        La[2] = *reinterpret_cast<const float4*>(t10 + n0);
        La[3] = *reinterpret_cast<const float4*>(t11 + n0);
        Lb[0] = *reinterpret_cast<const float4*>(t00 + n1);
        Lb[1] = *reinterpret_cast<const float4*>(t01 + n1);
        Lb[2] = *reinterpret_cast<const float4*>(t10 + n1);
        Lb[3] = *reinterpret_cast<const float4*>(t11 + n1);
    }
    __syncthreads();    // xstg chunk0 published

    // ---- layer 1: 9 chunks, 32x32x16 MFMA, pair-shared A ----
    f32x16 acc0, acc1;
    #pragma unroll
    for (int i = 0; i < 16; ++i) { acc0[i] = 0.0f; acc1[i] = 0.0f; }
    const int bn0 = (np*2)*32 + l31;        // B row for nt tile 0
    int cur = 0;
    #pragma unroll
    for (int kc = 0; kc < 9; ++kc) {
        // issue next W chunk loads (W1 kc+1, or W2 chunk 0 at kc==8)
        {
            const unsigned short* s = (kc < 8)
                ? (wsu + sp*W1LO + sn*KU1 + (kc+1)*32 + sh)
                : (wsu + W2OF + sp*W2LO + sn*128 + sh);
            wa = *reinterpret_cast<const uint4*>(s);
            wb = *reinterpret_cast<const uint4*>(s + 8);
        }
        // stage chunk kc+1 into alternate pair buffer
        if (kc < 8) {
            const int c = kc + 1;
            float f0[4], f1[4];
            f0[0] = w00*La[0].x + w01*La[1].x + w10*La[2].x + w11*La[3].x;
            f0[1] = w00*La[0].y + w01*La[1].y + w10*La[2].y + w11*La[3].y;
            f0[2] = w00*La[0].z + w01*La[1].z + w10*La[2].z + w11*La[3].z;
            f0[3] = w00*La[0].w + w01*La[1].w + w10*La[2].w + w11*La[3].w;
            if (c == 8) {
                f1[0]=0.f; f1[1]=0.f; f1[2]=0.f; f1[3]=0.f;
            } else {
                f1[0] = w00*Lb[0].x + w01*Lb[1].x + w10*Lb[2].x + w11*Lb[3].x;
                f1[1] = w00*Lb[0].y + w01*Lb[1].y + w10*Lb[2].y + w11*Lb[3].y;
                f1[2] = w00*Lb[0].z + w01*Lb[1].z + w10*Lb[2].z + w11*Lb[3].z;
                f1[3] = w00*Lb[0].w + w01*Lb[1].w + w10*Lb[2].w + w11*Lb[3].w;
            }
            uint4 u0, u1;
            u0.x = packsplit(f0[0]); u0.y = packsplit(f0[1]);
            u0.z = packsplit(f0[2]); u0.w = packsplit(f0[3]);
            u1.x = packsplit(f1[0]); u1.y = packsplit(f1[1]);
            u1.z = packsplit(f1[2]); u1.w = packsplit(f1[3]);
            unsigned int* xw = &xstg[mt][cur^1][rit*STGS];
            *reinterpret_cast<uint4*>(xw + qq*4)      = u0;
            *reinterpret_cast<uint4*>(xw + 16 + qq*4) = u1;
            // issue texels for chunk kc+2
            if (kc < 7) {
                const int n0 = (kc+2)*32 - 16 + qq*4;
                La[0] = *reinterpret_cast<const float4*>(t00 + n0);
                La[1] = *reinterpret_cast<const float4*>(t01 + n0);
                La[2] = *reinterpret_cast<const float4*>(t10 + n0);
                La[3] = *reinterpret_cast<const float4*>(t11 + n0);
                if (kc < 6) {
                    const int n1 = n0 + 16;
                    Lb[0] = *reinterpret_cast<const float4*>(t00 + n1);
                    Lb[1] = *reinterpret_cast<const float4*>(t01 + n1);
                    Lb[2] = *reinterpret_cast<const float4*>(t10 + n1);
                    Lb[3] = *reinterpret_cast<const float4*>(t11 + n1);
                }
            }
        }
        // MFMA sweep: 2 K-steps x 2 N-tiles x 3 passes
        {
            const unsigned int* xb = &xstg[mt][cur][0];
            #pragma unroll
            for (int ks = 0; ks < 2; ++ks) {
                const uint4 ua = *reinterpret_cast<const uint4*>(xb + l31*STGS + ks*16 + lh*8);
                const uint4 ub = *reinterpret_cast<const uint4*>(xb + l31*STGS + ks*16 + lh*8 + 4);
                bf16x8 ah, al;
                unpack8(ua, ub, ah, al);
                const unsigned short* wk = ldsW + cur*WBUF + ks*16 + lh*8;
                {
                    const unsigned short* wp = wk + bn0*WROW;
                    const bf16x8 bh = *(const bf16x8*)(wp);
                    const bf16x8 bl = *(const bf16x8*)(wp + WPLANE);
                    acc0 = __builtin_amdgcn_mfma_f32_32x32x16_bf16(ah, bh, acc0, 0, 0, 0);
                    acc0 = __builtin_amdgcn_mfma_f32_32x32x16_bf16(al, bh, acc0, 0, 0, 0);
                    acc0 = __builtin_amdgcn_mfma_f32_32x32x16_bf16(ah, bl, acc0, 0, 0, 0);
                }
                {
                    const unsigned short* wp = wk + (bn0 + 32)*WROW;
                    const bf16x8 bh = *(const bf16x8*)(wp);
                    const bf16x8 bl = *(const bf16x8*)(wp + WPLANE);
                    acc1 = __builtin_amdgcn_mfma_f32_32x32x16_bf16(ah, bh, acc1, 0, 0, 0);
                    acc1 = __builtin_amdgcn_mfma_f32_32x32x16_bf16(al, bh, acc1, 0, 0, 0);
                    acc1 = __builtin_amdgcn_mfma_f32_32x32x16_bf16(ah, bl, acc1, 0, 0, 0);
                }
            }
        }
        // write next W chunk to alternate buffer, publish
        {
            unsigned short* d = ldsW + (cur^1)*WBUF + sp*WPLANE + sn*WROW + sh;
            *reinterpret_cast<uint4*>(d)     = wa;
            *reinterpret_cast<uint4*>(d + 8) = wb;
        }
        __syncthreads();
        cur ^= 1;
    }

    // ---- bias+relu+pack -> h1 (cross-np rows: barrier after) ----
    {
        const float b1v0 = b1[bn0], b1v1 = b1[bn0 + 32];
        #pragma unroll
        for (int j = 0; j < 16; ++j) {
            const int row = mt*32 + (j & 3) + 8*(j >> 2) + 4*lh;
            h1p[row*H1S + bn0]      = packsplit(fmaxf(acc0[j] + b1v0, 0.0f));
            h1p[row*H1S + bn0 + 32] = packsplit(fmaxf(acc1[j] + b1v1, 0.0f));
        }
    }
    __syncthreads();

    // ---- layer 2: 4 chunks, A from h1 (pair-shared), W2 dbuf in LDS ----
    #pragma unroll
    for (int i = 0; i < 16; ++i) { acc0[i] = 0.0f; acc1[i] = 0.0f; }
    #pragma unroll
    for (int kc = 0; kc < 4; ++kc) {
        if (kc < 3) {
            const unsigned short* s = wsu + W2OF + sp*W2LO + sn*128 + (kc+1)*32 + sh;
            wa = *reinterpret_cast<const uint4*>(s);
            wb = *reinterpret_cast<const uint4*>(s + 8);
        }
        const unsigned int* hb = h1p + (mt*32 + l31)*H1S + kc*32;
        #pragma unroll
        for (int ks = 0; ks < 2; ++ks) {
            const uint4 ua = *reinterpret_cast<const uint4*>(hb + ks*16 + lh*8);
            const uint4 ub = *reinterpret_cast<const uint4*>(hb + ks*16 + lh*8 + 4);
            bf16x8 ah, al;
            unpack8(ua, ub, ah, al);
            const unsigned short* wk = ldsW + cur*WBUF + ks*16 + lh*8;
            {
                const unsigned short* wp = wk + bn0*WROW;
                const bf16x8 bh = *(const bf16x8*)(wp);
                const bf16x8 bl = *(const bf16x8*)(wp + WPLANE);
                acc0 = __builtin_amdgcn_mfma_f32_32x32x16_bf16(ah, bh, acc0, 0, 0, 0);
                acc0 = __builtin_amdgcn_mfma_f32_32x32x16_bf16(al, bh, acc0, 0, 0, 0);
                acc0 = __builtin_amdgcn_mfma_f32_32x32x16_bf16(ah, bl, acc0, 0, 0, 0);
            }
            {
                const unsigned short* wp = wk + (bn0 + 32)*WROW;
                const bf16x8 bh = *(const bf16x8*)(wp);
                const bf16x8 bl = *(const bf16x8*)(wp + WPLANE);
                acc1 = __builtin_amdgcn_mfma_f32_32x32x16_bf16(ah, bh, acc1, 0, 0, 0);
                acc1 = __builtin_amdgcn_mfma_f32_32x32x16_bf16(al, bh, acc1, 0, 0, 0);
                acc1 = __builtin_amdgcn_mfma_f32_32x32x16_bf16(ah, bl, acc1, 0, 0, 0);
            }
        }
        if (kc < 3) {
            unsigned short* d = ldsW + (cur^1)*WBUF + sp*WPLANE + sn*WROW + sh;
            *reinterpret_cast<uint4*>(d)     = wa;
            *reinterpret_cast<uint4*>(d + 8) = wb;
            __syncthreads();
            cur ^= 1;
        }
    }

    // ---- readout: pr[16 rows][4] then butterfly-reduce over 32 cols ----
    {
        const float b2v0 = b2[bn0], b2v1 = b2[bn0 + 32];
        const float4 wr0 = *reinterpret_cast<const float4*>(Wr + bn0*4);
        const float4 wr1 = *reinterpret_cast<const float4*>(Wr + (bn0+32)*4);
        float pr[16][4];
        #pragma unroll
        for (int j = 0; j < 16; ++j) {
            const float h0 = fmaxf(acc0[j] + b2v0, 0.0f);
            const float h1v = fmaxf(acc1[j] + b2v1, 0.0f);
            pr[j][0] = h0*wr0.x + h1v*wr1.x;
            pr[j][1] = h0*wr0.y + h1v*wr1.y;
            pr[j][2] = h0*wr0.z + h1v*wr1.z;
            pr[j][3] = h0*wr0.w + h1v*wr1.w;
        }
        #pragma unroll
        for (int m = 1; m <= 16; m <<= 1)
            #pragma unroll
            for (int j = 0; j < 16; ++j)
                #pragma unroll
                for (int q = 0; q < 4; ++q)
                    pr[j][q] += __shfl_xor(pr[j][q], m, 64);
        if (l31 == 0) {
            #pragma unroll
            for (int j = 0; j < 16; ++j) {
                const int row = mt*32 + (j & 3) + 8*(j >> 2) + 4*lh;
                float4 o;
                o.x = pr[j][0]; o.y = pr[j][1]; o.z = pr[j][2]; o.w = pr[j][3];
                *reinterpret_cast<float4*>(&s_part[np][row][0]) = o;
            }
        }
    }
    __syncthreads();

    // ---- render inline: wave 0, lane = sample ----
    if (t < NSAMP) {
        const int p = t;
        const float o0 = 0.5f*((s_part[0][p][0] + s_part[1][p][0]) + (s_part[0][64+p][0] + s_part[1][64+p][0])) + br[0];
        const float o1 = 0.5f*((s_part[0][p][1] + s_part[1][p][1]) + (s_part[0][64+p][1] + s_part[1][64+p][1])) + br[1];
        const float o2 = 0.5f*((s_part[0][p][2] + s_part[1][p][2]) + (s_part[0][64+p][2] + s_part[1][64+p][2])) + br[2];
        const float o3 = 0.5f*((s_part[0][p][3] + s_part[1][p][3]) + (s_part[0][64+p][3] + s_part[1][64+p][3])) + br[3];
        const float c0 = 1.0f/(1.0f + __expf(-o0));
        const float c1 = 1.0f/(1.0f + __expf(-o1));
        const float c2 = 1.0f/(1.0f + __expf(-o2));
        const float dens = fmaxf(o3, 0.0f);
        const float zp = ZNEAR + p * STEP;
        const float zn = ZNEAR + (p+1) * STEP;
        const float dlast = (ZNEAR + 63*STEP) - (ZNEAR + 62*STEP);
        const float dist = (p == NSAMP-1) ? dlast : (zn - zp);
        const float alpha = 1.0f - __expf(-dens*dist);
        float scan = 1.0f - alpha + 1e-10f;
        #pragma unroll
        for (int off = 1; off < 64; off <<= 1) {
            const float vsh = __shfl_up(scan, off, 64);
            if (p >= off) scan *= vsh;
        }
        float trans = __shfl_up(scan, 1, 64);
        if (p == 0) trans = 1.0f;
        const float w = alpha * trans;
        float s0 = w*c0, s1 = w*c1, s2 = w*c2, sd = w*zp;
        #pragma unroll
        for (int m = 32; m > 0; m >>= 1) {
            s0 += __shfl_xor(s0, m, 64);
            s1 += __shfl_xor(s1, m, 64);
            s2 += __shfl_xor(s2, m, 64);
            sd += __shfl_xor(sd, m, 64);
        }
        if (p == 0) {
            out[r*3+0] = s0; out[r*3+1] = s1; out[r*3+2] = s2;
            out[NRAYS*3 + r] = sd;
        }
    }
}

extern "C" void kernel_launch(void* const* d_in, const int* in_sizes, int n_in,
                              void* d_out, int out_size, void* d_ws, size_t ws_size,
                              hipStream_t stream) {
    const float* rayo   = (const float*)d_in[0];
    const float* rayd   = (const float*)d_in[1];
    const float* images = (const float*)d_in[2];
    const float* intr   = (const float*)d_in[3];
    const float* einv   = (const float*)d_in[4];
    const float* feats  = (const float*)d_in[5];
    const float* W1     = (const float*)d_in[6];
    const float* b1     = (const float*)d_in[7];
    const float* W2     = (const float*)d_in[8];
    const float* b2     = (const float*)d_in[9];
    const float* Wr     = (const float*)d_in[10];
    const float* br     = (const float*)d_in[11];
    float* out = (float*)d_out;
    unsigned short* wsu = (unsigned short*)d_ws;                 // W split planes (213 KB)

    hipLaunchKernelGGL(nerf_prep, dim3(208), dim3(256), 0, stream, W1, W2, wsu);
    hipLaunchKernelGGL(nerf_main, dim3(NRAYS), dim3(512), 0, stream,
                       rayo, rayd, images, intr, einv, feats, b1, b2, Wr, br, wsu, out);
}

// Round 14
// 50.446 us; speedup vs baseline: 1.2096x; 1.2096x over previous
//
#include <hip/hip_runtime.h>
#include <math.h>

#define NRAYS 512
#define NSAMP 64
#define IMH 480
#define IMW 640
#define NFEAT 256
#define ZNEAR 0.7f
#define ZFAR 1.5f
#define KU1 288          // W1 row length (ushorts): k-map 0-8 meta, 9-15 zero, 16-271 feats, 272-287 zero
#define W1LO 36864       // ushort offset of W1 lo plane
#define W2OF 73728       // ushort offset of W2 hi plane
#define W2LO 16384       // relative ushort offset of W2 lo plane
#define H1S 132          // h1 packed row stride (u32)
#define STGS 36          // x staging row stride (u32)
#define WROW 40          // LDS W-chunk row stride (ushorts, 80B)
#define WPLANE 5120      // 128*WROW: lo-plane offset within a chunk buffer (ushorts)
#define WBUF 10240       // one chunk buffer = 2 planes (ushorts)

typedef __attribute__((ext_vector_type(8))) short bf16x8;
typedef __attribute__((ext_vector_type(16))) float f32x16;

__device__ __forceinline__ unsigned short bf16rne(float f) {
    unsigned int u = __builtin_bit_cast(unsigned int, f);
    unsigned int r = (u + 0x7FFFu + ((u >> 16) & 1u)) >> 16;
    return (unsigned short)r;
}
__device__ __forceinline__ float bf16tof(unsigned short h) {
    unsigned int u = ((unsigned int)h) << 16;
    return __builtin_bit_cast(float, u);
}
__device__ __forceinline__ unsigned int packsplit(float v) {
    const unsigned short h = bf16rne(v);
    const unsigned short l = bf16rne(v - bf16tof(h));
    return (((unsigned int)h) << 16) | (unsigned int)l;
}
__device__ __forceinline__ void unpack8(uint4 a, uint4 b, bf16x8& hi, bf16x8& lo) {
    union { bf16x8 v; unsigned short u[8]; } H, L;
    const unsigned int w[8] = {a.x, a.y, a.z, a.w, b.x, b.y, b.z, b.w};
    #pragma unroll
    for (int i = 0; i < 8; ++i) {
        H.u[i] = (unsigned short)(w[i] >> 16);
        L.u[i] = (unsigned short)(w[i] & 0xFFFFu);
    }
    hi = H.v; lo = L.v;
}

// ---- prep: transpose + bf16-split W1 -> [128][288] and W2 -> [128][128] ----
__global__ __launch_bounds__(256)
void nerf_prep(const float* __restrict__ W1, const float* __restrict__ W2,
               unsigned short* __restrict__ wsu) {
    const int i = blockIdx.x * 256 + threadIdx.x;
    if (i < 36864) {
        const int n = i / KU1, k = i % KU1;
        float val = 0.0f;
        if (k < 9) val = W1[k * 128 + n];
        else if (k >= 16 && k < 272) val = W1[(k - 7) * 128 + n];
        const unsigned short h = bf16rne(val);
        wsu[n * KU1 + k] = h;
        wsu[W1LO + n * KU1 + k] = bf16rne(val - bf16tof(h));
    } else if (i < 53248) {
        const int j = i - 36864;
        const int n = j >> 7, k = j & 127;
        const float val = W2[k * 128 + n];
        const unsigned short h = bf16rne(val);
        wsu[W2OF + n * 128 + k] = h;
        wsu[W2OF + W2LO + n * 128 + k] = bf16rne(val - bf16tof(h));
    }
}

// ---- main: block = ray, 512 thr = 8 waves. Wave w: M-tile mt=w>>1 (32 rows),
// N-half np=w&1. 32x32x16 MFMA (B LDS traffic halved vs 16x16x32). Pair
// (2mt,2mt+1) shares A-frags via pair x-staging dbuf published by the W
// barrier. Readout = compacting fold (64 shfl, not 320). Fused render.
__global__ __launch_bounds__(512, 2)
void nerf_main(const float* __restrict__ rayo,
               const float* __restrict__ rayd,
               const float* __restrict__ images,
               const float* __restrict__ intr,
               const float* __restrict__ einv,
               const float* __restrict__ feats,
               const float* __restrict__ b1,
               const float* __restrict__ b2,
               const float* __restrict__ Wr,
               const float* __restrict__ br,
               const unsigned short* __restrict__ wsu,
               float* __restrict__ out) {
    __shared__ float s_meta[128][12];                // 6144B: o4 | wx wy | cam xyz
    __shared__ float s_cdir[2][4];
    __shared__ unsigned int h1p[128 * H1S];          // 67584B packed hi|lo
    __shared__ unsigned short ldsW[2 * WBUF];        // 40960B W-chunk dbuf
    __shared__ unsigned int xstg[4][2][32 * STGS];   // 36864B pair x-staging dbuf
    __shared__ float s_part[2][128][4];              // 4096B readout partials

    const int t = threadIdx.x;
    const int r = blockIdx.x;
    const int w8 = __builtin_amdgcn_readfirstlane(t >> 6);
    const int mt = w8 >> 1;                 // M-tile 0..3
    const int np = w8 & 1;                  // N-half
    const int lane = t & 63;
    const int l31 = lane & 31;
    const int lh = lane >> 5;
    const int sq = lane >> 2;               // staging row-within-16
    const int qq = lane & 3;                // staging dim-quad
    const int vW = w8 >> 2;                 // view of this wave's rows
    const int rit = np * 16 + sq;           // staged row within M-tile
    constexpr float STEP = (ZFAR - ZNEAR) / (NSAMP - 1);

    // W staging role: each thread moves 32B of a chunk
    const int sp = t >> 8;                  // plane
    const int sn = (t & 255) >> 1;          // row n
    const int sh = (t & 1) * 16;            // col half (ushorts)

    // issue W1 chunk 0 loads (hide under meta prep)
    uint4 wa, wb;
    {
        const unsigned short* s = wsu + sp*W1LO + sn*KU1 + sh;
        wa = *reinterpret_cast<const uint4*>(s);
        wb = *reinterpret_cast<const uint4*>(s + 8);
    }

    // ---- projection prep: threads 0..127 = global row (view, sample) ----
    if (t < 128) {
        const int vv = t >> 6, p = t & 63;
        const float ox = rayo[r*3+0], oy = rayo[r*3+1], oz = rayo[r*3+2];
        const float dx = rayd[r*3+0], dy = rayd[r*3+1], dz = rayd[r*3+2];
        const float z = ZNEAR + p * STEP;
        const float wxp = ox + z*dx, wyp = oy + z*dy, wzp = oz + z*dz;
        const float* E = einv + vv*16;
        const float cx = E[0]*wxp + E[1]*wyp + E[2]*wzp + E[3];
        const float cy = E[4]*wxp + E[5]*wyp + E[6]*wzp + E[7];
        const float cz = E[8]*wxp + E[9]*wyp + E[10]*wzp + E[11];
        const float cw = E[12]*wxp + E[13]*wyp + E[14]*wzp + E[15];
        const float* Km = intr + vv*16;
        const float px = Km[0]*cx + Km[1]*cy + Km[2]*cz + Km[3]*cw;
        const float py = Km[4]*cx + Km[5]*cy + Km[6]*cz + Km[7]*cw;
        const float pz = Km[8]*cx + Km[9]*cy + Km[10]*cz + Km[11]*cw;
        const float inv = pz + 1e-8f;
        float fx = px / inv, fy = py / inv;
        fx = fminf(fmaxf(fx, 0.0f), (float)(IMW-1));
        fy = fminf(fmaxf(fy, 0.0f), (float)(IMH-1));
        const int x0 = (int)floorf(fx), y0 = (int)floorf(fy);
        const int x1 = min(x0+1, IMW-1), y1 = min(y0+1, IMH-1);
        const int base = vv*IMH*IMW;
        int4 o4; o4.x = (base + y0*IMW + x0) * NFEAT;
                 o4.y = (base + y0*IMW + x1) * NFEAT;
                 o4.z = (base + y1*IMW + x0) * NFEAT;
                 o4.w = (base + y1*IMW + x1) * NFEAT;
        *(int4*)&s_meta[t][0] = o4;
        s_meta[t][4] = fx - (float)x0;
        s_meta[t][5] = fy - (float)y0;
        s_meta[t][6] = cx; s_meta[t][7] = cy; s_meta[t][8] = cz;
        if (p == 0) {
            s_cdir[vv][0] = E[0]*dx + E[1]*dy + E[2]*dz;
            s_cdir[vv][1] = E[4]*dx + E[5]*dy + E[6]*dz;
            s_cdir[vv][2] = E[8]*dx + E[9]*dy + E[10]*dz;
        }
    }
    // write W1 chunk 0 -> buffer 0 (covered by same barrier)
    {
        unsigned short* d = ldsW + sp*WPLANE + sn*WROW + sh;
        *reinterpret_cast<uint4*>(d)     = wa;
        *reinterpret_cast<uint4*>(d + 8) = wb;
    }
    __syncthreads();

    // ---- staging meta for this lane's row (w8*16 + sq) ----
    const float* mg = s_meta[w8*16 + sq];
    const int4 og = *(const int4*)mg;
    const float wx = mg[4], wy = mg[5];
    const float w00 = (1.f-wx)*(1.f-wy), w01 = wx*(1.f-wy);
    const float w10 = (1.f-wx)*wy,       w11 = wx*wy;
    const float* t00 = feats + og.x;
    const float* t01 = feats + og.y;
    const float* t10 = feats + og.z;
    const float* t11 = feats + og.w;

    float ia = 0.f, ib = 0.f;
    if (qq == 1 || qq == 2) {
        const int i00 = (og.x >> 8) * 3, i01 = (og.y >> 8) * 3;
        const int i10 = (og.z >> 8) * 3, i11 = (og.w >> 8) * 3;
        if (qq == 1) {
            ia = 2.0f*(w00*images[i00+0] + w01*images[i01+0] + w10*images[i10+0] + w11*images[i11+0]) - 1.0f;
            ib = 2.0f*(w00*images[i00+1] + w01*images[i01+1] + w10*images[i10+1] + w11*images[i11+1]) - 1.0f;
        } else {
            ia = 2.0f*(w00*images[i00+2] + w01*images[i01+2] + w10*images[i10+2] + w11*images[i11+2]) - 1.0f;
        }
    }

    float4 La[4], Lb[4];
    {   // texels chunk0 sub1 (dims 16-31 = feats 0-15)
        const int f1 = qq*4;
        Lb[0] = *reinterpret_cast<const float4*>(t00 + f1);
        Lb[1] = *reinterpret_cast<const float4*>(t01 + f1);
        Lb[2] = *reinterpret_cast<const float4*>(t10 + f1);
        Lb[3] = *reinterpret_cast<const float4*>(t11 + f1);
    }
    // ---- stage chunk 0 into pair buffer 0 ----
    {
        float f0[4], f1[4];
        if (qq == 0)      { f0[0]=mg[6]; f0[1]=mg[7]; f0[2]=mg[8]; f0[3]=s_cdir[vW][0]; }
        else if (qq == 1) { f0[0]=s_cdir[vW][1]; f0[1]=s_cdir[vW][2]; f0[2]=ia; f0[3]=ib; }
        else if (qq == 2) { f0[0]=ia; f0[1]=0.f; f0[2]=0.f; f0[3]=0.f; }
        else              { f0[0]=0.f; f0[1]=0.f; f0[2]=0.f; f0[3]=0.f; }
        f1[0] = w00*Lb[0].x + w01*Lb[1].x + w10*Lb[2].x + w11*Lb[3].x;
        f1[1] = w00*Lb[0].y + w01*Lb[1].y + w10*Lb[2].y + w11*Lb[3].y;
        f1[2] = w00*Lb[0].z + w01*Lb[1].z + w10*Lb[2].z + w11*Lb[3].z;
        f1[3] = w00*Lb[0].w + w01*Lb[1].w + w10*Lb[2].w + w11*Lb[3].w;
        uint4 u0, u1;
        u0.x = packsplit(f0[0]); u0.y = packsplit(f0[1]);
        u0.z = packsplit(f0[2]); u0.w = packsplit(f0[3]);
        u1.x = packsplit(f1[0]); u1.y = packsplit(f1[1]);
        u1.z = packsplit(f1[2]); u1.w = packsplit(f1[3]);
        unsigned int* xw = &xstg[mt][0][rit*STGS];
        *reinterpret_cast<uint4*>(xw + qq*4)      = u0;
        *reinterpret_cast<uint4*>(xw + 16 + qq*4) = u1;
    }
    {   // texels for chunk 1 (sub0 feats 16.., sub1 feats 32..)
        const int n0 = 16 + qq*4, n1 = 32 + qq*4;
        La[0] = *reinterpret_cast<const float4*>(t00 + n0);
        La[1] = *reinterpret_cast<const float4*>(t01 + n0);
        La[2] = *reinterpret_cast<const float4*>(t10 + n0);
        La[3] = *reinterpret_cast<const float4*>(t11 + n0);
        Lb[0] = *reinterpret_cast<const float4*>(t00 + n1);
        Lb[1] = *reinterpret_cast<const float4*>(t01 + n1);
        Lb[2] = *reinterpret_cast<const float4*>(t10 + n1);
        Lb[3] = *reinterpret_cast<const float4*>(t11 + n1);
    }
    __syncthreads();    // xstg chunk0 published

    // ---- layer 1: 9 chunks, 32x32x16 MFMA, pair-shared A ----
    f32x16 acc0, acc1;
    #pragma unroll
    for (int i = 0; i < 16; ++i) { acc0[i] = 0.0f; acc1[i] = 0.0f; }
    const int bn0 = (np*2)*32 + l31;        // B row for nt tile 0
    int cur = 0;
    #pragma unroll
    for (int kc = 0; kc < 9; ++kc) {
        // issue next W chunk loads (W1 kc+1, or W2 chunk 0 at kc==8)
        {
            const unsigned short* s = (kc < 8)
                ? (wsu + sp*W1LO + sn*KU1 + (kc+1)*32 + sh)
                : (wsu + W2OF + sp*W2LO + sn*128 + sh);
            wa = *reinterpret_cast<const uint4*>(s);
            wb = *reinterpret_cast<const uint4*>(s + 8);
        }
        // stage chunk kc+1 into alternate pair buffer
        if (kc < 8) {
            const int c = kc + 1;
            float f0[4], f1[4];
            f0[0] = w00*La[0].x + w01*La[1].x + w10*La[2].x + w11*La[3].x;
            f0[1] = w00*La[0].y + w01*La[1].y + w10*La[2].y + w11*La[3].y;
            f0[2] = w00*La[0].z + w01*La[1].z + w10*La[2].z + w11*La[3].z;
            f0[3] = w00*La[0].w + w01*La[1].w + w10*La[2].w + w11*La[3].w;
            if (c == 8) {
                f1[0]=0.f; f1[1]=0.f; f1[2]=0.f; f1[3]=0.f;
            } else {
                f1[0] = w00*Lb[0].x + w01*Lb[1].x + w10*Lb[2].x + w11*Lb[3].x;
                f1[1] = w00*Lb[0].y + w01*Lb[1].y + w10*Lb[2].y + w11*Lb[3].y;
                f1[2] = w00*Lb[0].z + w01*Lb[1].z + w10*Lb[2].z + w11*Lb[3].z;
                f1[3] = w00*Lb[0].w + w01*Lb[1].w + w10*Lb[2].w + w11*Lb[3].w;
            }
            uint4 u0, u1;
            u0.x = packsplit(f0[0]); u0.y = packsplit(f0[1]);
            u0.z = packsplit(f0[2]); u0.w = packsplit(f0[3]);
            u1.x = packsplit(f1[0]); u1.y = packsplit(f1[1]);
            u1.z = packsplit(f1[2]); u1.w = packsplit(f1[3]);
            unsigned int* xw = &xstg[mt][cur^1][rit*STGS];
            *reinterpret_cast<uint4*>(xw + qq*4)      = u0;
            *reinterpret_cast<uint4*>(xw + 16 + qq*4) = u1;
            // issue texels for chunk kc+2
            if (kc < 7) {
                const int n0 = (kc+2)*32 - 16 + qq*4;
                La[0] = *reinterpret_cast<const float4*>(t00 + n0);
                La[1] = *reinterpret_cast<const float4*>(t01 + n0);
                La[2] = *reinterpret_cast<const float4*>(t10 + n0);
                La[3] = *reinterpret_cast<const float4*>(t11 + n0);
                if (kc < 6) {
                    const int n1 = n0 + 16;
                    Lb[0] = *reinterpret_cast<const float4*>(t00 + n1);
                    Lb[1] = *reinterpret_cast<const float4*>(t01 + n1);
                    Lb[2] = *reinterpret_cast<const float4*>(t10 + n1);
                    Lb[3] = *reinterpret_cast<const float4*>(t11 + n1);
                }
            }
        }
        // MFMA sweep: 2 K-steps x 2 N-tiles x 3 passes
        {
            const unsigned int* xb = &xstg[mt][cur][0];
            #pragma unroll
            for (int ks = 0; ks < 2; ++ks) {
                const uint4 ua = *reinterpret_cast<const uint4*>(xb + l31*STGS + ks*16 + lh*8);
                const uint4 ub = *reinterpret_cast<const uint4*>(xb + l31*STGS + ks*16 + lh*8 + 4);
                bf16x8 ah, al;
                unpack8(ua, ub, ah, al);
                const unsigned short* wk = ldsW + cur*WBUF + ks*16 + lh*8;
                {
                    const unsigned short* wp = wk + bn0*WROW;
                    const bf16x8 bh = *(const bf16x8*)(wp);
                    const bf16x8 bl = *(const bf16x8*)(wp + WPLANE);
                    acc0 = __builtin_amdgcn_mfma_f32_32x32x16_bf16(ah, bh, acc0, 0, 0, 0);
                    acc0 = __builtin_amdgcn_mfma_f32_32x32x16_bf16(al, bh, acc0, 0, 0, 0);
                    acc0 = __builtin_amdgcn_mfma_f32_32x32x16_bf16(ah, bl, acc0, 0, 0, 0);
                }
                {
                    const unsigned short* wp = wk + (bn0 + 32)*WROW;
                    const bf16x8 bh = *(const bf16x8*)(wp);
                    const bf16x8 bl = *(const bf16x8*)(wp + WPLANE);
                    acc1 = __builtin_amdgcn_mfma_f32_32x32x16_bf16(ah, bh, acc1, 0, 0, 0);
                    acc1 = __builtin_amdgcn_mfma_f32_32x32x16_bf16(al, bh, acc1, 0, 0, 0);
                    acc1 = __builtin_amdgcn_mfma_f32_32x32x16_bf16(ah, bl, acc1, 0, 0, 0);
                }
            }
        }
        // write next W chunk to alternate buffer, publish
        {
            unsigned short* d = ldsW + (cur^1)*WBUF + sp*WPLANE + sn*WROW + sh;
            *reinterpret_cast<uint4*>(d)     = wa;
            *reinterpret_cast<uint4*>(d + 8) = wb;
        }
        __syncthreads();
        cur ^= 1;
    }

    // ---- bias+relu+pack -> h1 (cross-np rows: barrier after) ----
    {
        const float b1v0 = b1[bn0], b1v1 = b1[bn0 + 32];
        #pragma unroll
        for (int j = 0; j < 16; ++j) {
            const int row = mt*32 + (j & 3) + 8*(j >> 2) + 4*lh;
            h1p[row*H1S + bn0]      = packsplit(fmaxf(acc0[j] + b1v0, 0.0f));
            h1p[row*H1S + bn0 + 32] = packsplit(fmaxf(acc1[j] + b1v1, 0.0f));
        }
    }
    __syncthreads();

    // ---- layer 2: 4 chunks, A from h1 (pair-shared), W2 dbuf in LDS ----
    #pragma unroll
    for (int i = 0; i < 16; ++i) { acc0[i] = 0.0f; acc1[i] = 0.0f; }
    #pragma unroll
    for (int kc = 0; kc < 4; ++kc) {
        if (kc < 3) {
            const unsigned short* s = wsu + W2OF + sp*W2LO + sn*128 + (kc+1)*32 + sh;
            wa = *reinterpret_cast<const uint4*>(s);
            wb = *reinterpret_cast<const uint4*>(s + 8);
        }
        const unsigned int* hb = h1p + (mt*32 + l31)*H1S + kc*32;
        #pragma unroll
        for (int ks = 0; ks < 2; ++ks) {
            const uint4 ua = *reinterpret_cast<const uint4*>(hb + ks*16 + lh*8);
            const uint4 ub = *reinterpret_cast<const uint4*>(hb + ks*16 + lh*8 + 4);
            bf16x8 ah, al;
            unpack8(ua, ub, ah, al);
            const unsigned short* wk = ldsW + cur*WBUF + ks*16 + lh*8;
            {
                const unsigned short* wp = wk + bn0*WROW;
                const bf16x8 bh = *(const bf16x8*)(wp);
                const bf16x8 bl = *(const bf16x8*)(wp + WPLANE);
                acc0 = __builtin_amdgcn_mfma_f32_32x32x16_bf16(ah, bh, acc0, 0, 0, 0);
                acc0 = __builtin_amdgcn_mfma_f32_32x32x16_bf16(al, bh, acc0, 0, 0, 0);
                acc0 = __builtin_amdgcn_mfma_f32_32x32x16_bf16(ah, bl, acc0, 0, 0, 0);
            }
            {
                const unsigned short* wp = wk + (bn0 + 32)*WROW;
                const bf16x8 bh = *(const bf16x8*)(wp);
                const bf16x8 bl = *(const bf16x8*)(wp + WPLANE);
                acc1 = __builtin_amdgcn_mfma_f32_32x32x16_bf16(ah, bh, acc1, 0, 0, 0);
                acc1 = __builtin_amdgcn_mfma_f32_32x32x16_bf16(al, bh, acc1, 0, 0, 0);
                acc1 = __builtin_amdgcn_mfma_f32_32x32x16_bf16(ah, bl, acc1, 0, 0, 0);
            }
        }
        if (kc < 3) {
            unsigned short* d = ldsW + (cur^1)*WBUF + sp*WPLANE + sn*WROW + sh;
            *reinterpret_cast<uint4*>(d)     = wa;
            *reinterpret_cast<uint4*>(d + 8) = wb;
            __syncthreads();
            cur ^= 1;
        }
    }

    // ---- readout: compacting fold over l31 (64 shfl, not 320) ----
    {
        const float b2v0 = b2[bn0], b2v1 = b2[bn0 + 32];
        const float4 wr0 = *reinterpret_cast<const float4*>(Wr + bn0*4);
        const float4 wr1 = *reinterpret_cast<const float4*>(Wr + (bn0+32)*4);
        float pr[16][4];
        #pragma unroll
        for (int j = 0; j < 16; ++j) {
            const float h0 = fmaxf(acc0[j] + b2v0, 0.0f);
            const float h1v = fmaxf(acc1[j] + b2v1, 0.0f);
            pr[j][0] = h0*wr0.x + h1v*wr1.x;
            pr[j][1] = h0*wr0.y + h1v*wr1.y;
            pr[j][2] = h0*wr0.z + h1v*wr1.z;
            pr[j][3] = h0*wr0.w + h1v*wr1.w;
        }
        // fold: at step b, keep the j-half matching lane bit b, add partner's
        #pragma unroll
        for (int b = 0; b < 4; ++b) {
            const int m = 1 << b;
            const int Sh = 8 >> b;               // half-size of remaining array
            const bool hi = (l31 >> b) & 1;
            #pragma unroll
            for (int i = 0; i < 8; ++i) {
                if (i < Sh) {
                    #pragma unroll
                    for (int q = 0; q < 4; ++q) {
                        const float send = hi ? pr[i][q] : pr[Sh + i][q];
                        const float keep = hi ? pr[Sh + i][q] : pr[i][q];
                        const float rcv  = __shfl_xor(send, m, 64);
                        pr[i][q] = keep + rcv;
                    }
                }
            }
        }
        #pragma unroll
        for (int q = 0; q < 4; ++q)
            pr[0][q] += __shfl_xor(pr[0][q], 16, 64);
        if (l31 < 16) {
            const int jf = ((l31 & 1) << 3) | (((l31 >> 1) & 1) << 2)
                         | (((l31 >> 2) & 1) << 1) | ((l31 >> 3) & 1);
            const int row = mt*32 + (jf & 3) + 8*(jf >> 2) + 4*lh;
            float4 o;
            o.x = pr[0][0]; o.y = pr[0][1]; o.z = pr[0][2]; o.w = pr[0][3];
            *reinterpret_cast<float4*>(&s_part[np][row][0]) = o;
        }
    }
    __syncthreads();

    // ---- render inline: wave 0, lane = sample ----
    if (t < NSAMP) {
        const int p = t;
        const float o0 = 0.5f*((s_part[0][p][0] + s_part[1][p][0]) + (s_part[0][64+p][0] + s_part[1][64+p][0])) + br[0];
        const float o1 = 0.5f*((s_part[0][p][1] + s_part[1][p][1]) + (s_part[0][64+p][1] + s_part[1][64+p][1])) + br[1];
        const float o2 = 0.5f*((s_part[0][p][2] + s_part[1][p][2]) + (s_part[0][64+p][2] + s_part[1][64+p][2])) + br[2];
        const float o3 = 0.5f*((s_part[0][p][3] + s_part[1][p][3]) + (s_part[0][64+p][3] + s_part[1][64+p][3])) + br[3];
        const float c0 = 1.0f/(1.0f + __expf(-o0));
        const float c1 = 1.0f/(1.0f + __expf(-o1));
        const float c2 = 1.0f/(1.0f + __expf(-o2));
        const float dens = fmaxf(o3, 0.0f);
        const float zp = ZNEAR + p * STEP;
        const float zn = ZNEAR + (p+1) * STEP;
        const float dlast = (ZNEAR + 63*STEP) - (ZNEAR + 62*STEP);
        const float dist = (p == NSAMP-1) ? dlast : (zn - zp);
        const float alpha = 1.0f - __expf(-dens*dist);
        float scan = 1.0f - alpha + 1e-10f;
        #pragma unroll
        for (int off = 1; off < 64; off <<= 1) {
            const float vsh = __shfl_up(scan, off, 64);
            if (p >= off) scan *= vsh;
        }
        float trans = __shfl_up(scan, 1, 64);
        if (p == 0) trans = 1.0f;
        const float w = alpha * trans;
        float s0 = w*c0, s1 = w*c1, s2 = w*c2, sd = w*zp;
        #pragma unroll
        for (int m = 32; m > 0; m >>= 1) {
            s0 += __shfl_xor(s0, m, 64);
            s1 += __shfl_xor(s1, m, 64);
            s2 += __shfl_xor(s2, m, 64);
            sd += __shfl_xor(sd, m, 64);
        }
        if (p == 0) {
            out[r*3+0] = s0; out[r*3+1] = s1; out[r*3+2] = s2;
            out[NRAYS*3 + r] = sd;
        }
    }
}

extern "C" void kernel_launch(void* const* d_in, const int* in_sizes, int n_in,
                              void* d_out, int out_size, void* d_ws, size_t ws_size,
                              hipStream_t stream) {
    const float* rayo   = (const float*)d_in[0];
    const float* rayd   = (const float*)d_in[1];
    const float* images = (const float*)d_in[2];
    const float* intr   = (const float*)d_in[3];
    const float* einv   = (const float*)d_in[4];
    const float* feats  = (const float*)d_in[5];
    const float* W1     = (const float*)d_in[6];
    const float* b1     = (const float*)d_in[7];
    const float* W2     = (const float*)d_in[8];
    const float* b2     = (const float*)d_in[9];
    const float* Wr     = (const float*)d_in[10];
    const float* br     = (const float*)d_in[11];
    float* out = (float*)d_out;
    unsigned short* wsu = (unsigned short*)d_ws;                 // W split planes (213 KB)

    hipLaunchKernelGGL(nerf_prep, dim3(208), dim3(256), 0, stream, W1, W2, wsu);
    hipLaunchKernelGGL(nerf_main, dim3(NRAYS), dim3(512), 0, stream,
                       rayo, rayd, images, intr, einv, feats, b1, b2, Wr, br, wsu, out);
}